// Round 1
// baseline (487.564 us; speedup 1.0000x reference)
//
#include <hip/hip_runtime.h>
#include <stdint.h>

#define N_ROWS 16384
#define M_ROWS 16384
#define KDIM   512
#define BM 128
#define BN 128
#define BK 64
#define NCHUNK 4
#define CHUNK_ROWS (M_ROWS / NCHUNK)      // 4096
#define BT_PER_CHUNK (CHUNK_ROWS / BN)    // 32

typedef _Float16 half8 __attribute__((ext_vector_type(8)));
typedef float floatx4 __attribute__((ext_vector_type(4)));

__device__ __forceinline__ void async_ld16(const _Float16* g, _Float16* l) {
  __builtin_amdgcn_global_load_lds(
      (const __attribute__((address_space(1))) void*)g,
      (__attribute__((address_space(3))) void*)l, 16, 0, 0);
}

// Kernel 1: fp32 -> f16 conversion + per-row squared norms (fp32).
// grid = N_ROWS + M_ROWS blocks, 128 threads; one row per block (512 floats).
__global__ void conv_kernel(const float* __restrict__ A, const float* __restrict__ B,
                            _Float16* __restrict__ Ah, _Float16* __restrict__ Bh,
                            float* __restrict__ sq1, float* __restrict__ sq2) {
  int row = blockIdx.x;
  const float* src;
  _Float16* dst;
  float* sq;
  if (row < N_ROWS) {
    src = A + (size_t)row * KDIM;
    dst = Ah + (size_t)row * KDIM;
    sq = sq1 + row;
  } else {
    int r = row - N_ROWS;
    src = B + (size_t)r * KDIM;
    dst = Bh + (size_t)r * KDIM;
    sq = sq2 + r;
  }
  int t = threadIdx.x;  // 0..127, each handles 4 floats
  float4 v = ((const float4*)src)[t];
  union { _Float16 h[4]; uint2 u; } pk;
  pk.h[0] = (_Float16)v.x;
  pk.h[1] = (_Float16)v.y;
  pk.h[2] = (_Float16)v.z;
  pk.h[3] = (_Float16)v.w;
  ((uint2*)dst)[t] = pk.u;
  float s = v.x * v.x + v.y * v.y + v.z * v.z + v.w * v.w;
  #pragma unroll
  for (int off = 32; off; off >>= 1) s += __shfl_down(s, off, 64);
  __shared__ float ws2[2];
  if ((t & 63) == 0) ws2[t >> 6] = s;
  __syncthreads();
  if (t == 0) *sq = ws2[0] + ws2[1];
}

// Kernel 2: fused GEMM + running-min.
// Block: 256 threads (4 waves, 2x2 wave grid, 64x64 per wave, 4x4 16x16 frags).
// Grid: (N_ROWS/BM, NCHUNK). Each block: its 128 A-rows vs its 4096-row B chunk.
__global__ void __launch_bounds__(256)
gemm_min_kernel(const _Float16* __restrict__ Ah, const _Float16* __restrict__ Bh,
                const float* __restrict__ sq2, float* __restrict__ ws_min) {
  __shared__ __align__(16) _Float16 lsA[BM * BK];  // [row][k], row stride BK
  __shared__ __align__(16) _Float16 lsB[BN * BK];  // [col][k]
  __shared__ float lmin[2][BM];

  const int tid = threadIdx.x;
  const int lane = tid & 63;
  const int wv = tid >> 6;       // 0..3
  const int wr = wv >> 1;        // wave row (0..1)
  const int wc = wv & 1;         // wave col (0..1)
  const int fr = lane & 15;      // frag row/col index
  const int kg = lane >> 4;      // k-group (0..3), *8 halves

  const int rowBase = blockIdx.x * BM;
  const int chunk = blockIdx.y;
  const int colBase0 = chunk * CHUNK_ROWS;

  float runmin[4][4];
  #pragma unroll
  for (int i = 0; i < 4; i++)
    #pragma unroll
    for (int j = 0; j < 4; j++) runmin[i][j] = 3.0e38f;

  for (int bt = 0; bt < BT_PER_CHUNK; ++bt) {
    const int colBase = colBase0 + bt * BN;
    floatx4 acc[4][4];
    #pragma unroll
    for (int i = 0; i < 4; i++)
      #pragma unroll
      for (int j = 0; j < 4; j++) acc[i][j] = (floatx4){0.f, 0.f, 0.f, 0.f};

    for (int kb = 0; kb < KDIM / BK; ++kb) {
      const int kbase = kb * BK;
      // Stage A slice (128x64 f16 = 16KB) and B slice: 16 x 1KB wave-calls each.
      #pragma unroll
      for (int c = 0; c < 4; ++c) {
        const int slotByte = (wv * 4 + c) * 1024 + lane * 16;
        const int r = slotByte >> 7;            // /128 B per row
        const int kofs = (slotByte & 127) >> 1; // half index in row
        const _Float16* gA = Ah + (size_t)(rowBase + r) * KDIM + kbase + kofs;
        _Float16* lA = lsA + ((wv * 4 + c) << 9);  // 1KB = 512 halves
        async_ld16(gA, lA);
        const _Float16* gB = Bh + (size_t)(colBase + r) * KDIM + kbase + kofs;
        _Float16* lB = lsB + ((wv * 4 + c) << 9);
        async_ld16(gB, lB);
      }
      __syncthreads();
      #pragma unroll
      for (int ks = 0; ks < 2; ++ks) {
        half8 af[4], bf[4];
        #pragma unroll
        for (int i = 0; i < 4; i++) {
          const int arow = wr * 64 + i * 16 + fr;
          af[i] = *(const half8*)(lsA + arow * BK + ks * 32 + kg * 8);
          const int bcol = wc * 64 + i * 16 + fr;
          bf[i] = *(const half8*)(lsB + bcol * BK + ks * 32 + kg * 8);
        }
        #pragma unroll
        for (int i = 0; i < 4; i++)
          #pragma unroll
          for (int j = 0; j < 4; j++)
            acc[i][j] = __builtin_amdgcn_mfma_f32_16x16x32_f16(af[i], bf[j], acc[i][j], 0, 0, 0);
      }
      __syncthreads();
    }

    // Epilogue: cand = sq2[col] - 2*inner, fold into per-row running min.
    // C frag: col = lane&15, row = (lane>>4)*4 + reg.
    #pragma unroll
    for (int j = 0; j < 4; j++) {
      const int col = colBase + wc * 64 + j * 16 + fr;
      const float s2 = sq2[col];
      #pragma unroll
      for (int i = 0; i < 4; i++)
        #pragma unroll
        for (int r4 = 0; r4 < 4; r4++) {
          const float cand = fmaf(-2.f, acc[i][j][r4], s2);
          runmin[i][r4] = fminf(runmin[i][r4], cand);
        }
    }
  }

  // Min across the 16 columns held by a lane-group: butterfly over lane bits 0..3.
  #pragma unroll
  for (int i = 0; i < 4; i++)
    #pragma unroll
    for (int r4 = 0; r4 < 4; r4++) {
      float v = runmin[i][r4];
      v = fminf(v, __shfl_xor(v, 1, 64));
      v = fminf(v, __shfl_xor(v, 2, 64));
      v = fminf(v, __shfl_xor(v, 4, 64));
      v = fminf(v, __shfl_xor(v, 8, 64));
      runmin[i][r4] = v;
    }

  // Combine across the 2 column-waves via LDS, then write per-chunk row mins.
  if (fr == 0) {
    #pragma unroll
    for (int i = 0; i < 4; i++)
      #pragma unroll
      for (int r4 = 0; r4 < 4; r4++) {
        const int lrow = wr * 64 + i * 16 + (lane >> 4) * 4 + r4;
        lmin[wc][lrow] = runmin[i][r4];
      }
  }
  __syncthreads();
  if (tid < BM) {
    const float m = fminf(lmin[0][tid], lmin[1][tid]);
    ws_min[(size_t)chunk * N_ROWS + rowBase + tid] = m;
  }
}

// Kernel 3: final reduction across chunks + sqrt/relu/mean.
__global__ void final_kernel(const float* __restrict__ ws_min,
                             const float* __restrict__ sq1,
                             float* __restrict__ out) {
  float sum = 0.f;
  for (int r = threadIdx.x; r < N_ROWS; r += 1024) {
    float m = ws_min[r];
    #pragma unroll
    for (int c = 1; c < NCHUNK; c++) m = fminf(m, ws_min[(size_t)c * N_ROWS + r]);
    float d2 = sq1[r] + m;
    d2 = d2 > 0.f ? d2 : 0.f;
    float v = sqrtf(d2) - 0.1f;
    sum += v > 0.f ? v : 0.f;
  }
  #pragma unroll
  for (int off = 32; off; off >>= 1) sum += __shfl_down(sum, off, 64);
  __shared__ float ps[16];
  if ((threadIdx.x & 63) == 0) ps[threadIdx.x >> 6] = sum;
  __syncthreads();
  if (threadIdx.x == 0) {
    float t = 0.f;
    #pragma unroll
    for (int i = 0; i < 16; i++) t += ps[i];
    out[0] = t / (float)N_ROWS;
  }
}

extern "C" void kernel_launch(void* const* d_in, const int* in_sizes, int n_in,
                              void* d_out, int out_size, void* d_ws, size_t ws_size,
                              hipStream_t stream) {
  const float* A = (const float*)d_in[0];
  const float* B = (const float*)d_in[1];
  char* ws = (char*)d_ws;
  const size_t halfBytes = (size_t)N_ROWS * KDIM * 2;  // 16 MiB each
  _Float16* Ah = (_Float16*)ws;
  _Float16* Bh = (_Float16*)(ws + halfBytes);
  float* sq1 = (float*)(ws + 2 * halfBytes);
  float* sq2 = sq1 + N_ROWS;
  float* ws_min = sq2 + M_ROWS;

  conv_kernel<<<dim3(N_ROWS + M_ROWS), dim3(128), 0, stream>>>(A, B, Ah, Bh, sq1, sq2);
  gemm_min_kernel<<<dim3(N_ROWS / BM, NCHUNK), dim3(256), 0, stream>>>(Ah, Bh, sq2, ws_min);
  final_kernel<<<dim3(1), dim3(1024), 0, stream>>>(ws_min, sq1, (float*)d_out);
}

// Round 2
// 485.740 us; speedup vs baseline: 1.0038x; 1.0038x over previous
//
#include <hip/hip_runtime.h>
#include <stdint.h>

#define N_ROWS 16384
#define M_ROWS 16384
#define KDIM   512
#define BM 128
#define BN 128
#define BK 64
#define NCHUNK 8
#define CHUNK_ROWS (M_ROWS / NCHUNK)      // 2048
#define BT_PER_CHUNK (CHUNK_ROWS / BN)    // 16

typedef _Float16 half8 __attribute__((ext_vector_type(8)));
typedef float floatx4 __attribute__((ext_vector_type(4)));

__device__ __forceinline__ void async_ld16(const _Float16* g, _Float16* l) {
  __builtin_amdgcn_global_load_lds(
      (const __attribute__((address_space(1))) void*)g,
      (__attribute__((address_space(3))) void*)l, 16, 0, 0);
}

// Kernel 1: fp32 -> f16 conversion + per-row squared norms (fp32).
__global__ void conv_kernel(const float* __restrict__ A, const float* __restrict__ B,
                            _Float16* __restrict__ Ah, _Float16* __restrict__ Bh,
                            float* __restrict__ sq1, float* __restrict__ sq2) {
  int row = blockIdx.x;
  const float* src;
  _Float16* dst;
  float* sq;
  if (row < N_ROWS) {
    src = A + (size_t)row * KDIM;
    dst = Ah + (size_t)row * KDIM;
    sq = sq1 + row;
  } else {
    int r = row - N_ROWS;
    src = B + (size_t)r * KDIM;
    dst = Bh + (size_t)r * KDIM;
    sq = sq2 + r;
  }
  int t = threadIdx.x;  // 0..127, each handles 4 floats
  float4 v = ((const float4*)src)[t];
  union { _Float16 h[4]; uint2 u; } pk;
  pk.h[0] = (_Float16)v.x;
  pk.h[1] = (_Float16)v.y;
  pk.h[2] = (_Float16)v.z;
  pk.h[3] = (_Float16)v.w;
  ((uint2*)dst)[t] = pk.u;
  float s = v.x * v.x + v.y * v.y + v.z * v.z + v.w * v.w;
  #pragma unroll
  for (int off = 32; off; off >>= 1) s += __shfl_down(s, off, 64);
  __shared__ float ws2[2];
  if ((t & 63) == 0) ws2[t >> 6] = s;
  __syncthreads();
  if (t == 0) *sq = ws2[0] + ws2[1];
}

// Kernel 2: fused GEMM + running-min.
// LDS layout is XOR-swizzled: row r, 16B-slot s holds global chunk (s ^ (r&7)).
// The swizzle is applied on the global source address (global_load_lds's LDS
// dest must stay wave-uniform-base + lane*16); reads un-permute. This breaks
// the 16-way bank conflict of the 128B row stride down to free 2-way.
__global__ void __launch_bounds__(256, 4)
gemm_min_kernel(const _Float16* __restrict__ Ah, const _Float16* __restrict__ Bh,
                const float* __restrict__ sq2, float* __restrict__ ws_min) {
  __shared__ __align__(16) _Float16 lsA[BM * BK];  // [row][k], row stride 64 halves
  __shared__ __align__(16) _Float16 lsB[BN * BK];  // [col][k]
  __shared__ float lmin[2][BM];

  const int tid = threadIdx.x;
  const int lane = tid & 63;
  const int wv = tid >> 6;       // 0..3
  const int wr = wv >> 1;        // wave row (0..1)
  const int wc = wv & 1;         // wave col (0..1)
  const int fr = lane & 15;      // frag row/col index
  const int kg = lane >> 4;      // k-group (0..3), *8 halves
  const int frs = fr & 7;        // read-side swizzle key (arow&7 == fr&7)

  const int rowBase = blockIdx.x * BM;
  const int chunk = blockIdx.y;
  const int colBase0 = chunk * CHUNK_ROWS;

  // Staging geometry (per wave-call c): slotByte = (wv*4+c)*1024 + lane*16.
  const int r_st = (lane * 16) >> 7;         // row offset within 8-row group
  const int s_st = ((lane * 16) & 127) >> 4; // chunk-in-row 0..7
  const int kofs_st = (s_st ^ (r_st & 7)) * 8;  // swizzled source chunk (halves)

  float runmin[4][4];
  #pragma unroll
  for (int i = 0; i < 4; i++)
    #pragma unroll
    for (int j = 0; j < 4; j++) runmin[i][j] = 3.0e38f;

  for (int bt = 0; bt < BT_PER_CHUNK; ++bt) {
    const int colBase = colBase0 + bt * BN;
    floatx4 acc[4][4];
    #pragma unroll
    for (int i = 0; i < 4; i++)
      #pragma unroll
      for (int j = 0; j < 4; j++) acc[i][j] = (floatx4){0.f, 0.f, 0.f, 0.f};

    for (int kb = 0; kb < KDIM / BK; ++kb) {
      const int kbase = kb * BK;
      #pragma unroll
      for (int c = 0; c < 4; ++c) {
        const int slot = wv * 4 + c;          // 16 slots, 8 rows each
        const int r = slot * 8 + r_st;        // global row within tile
        const _Float16* gA = Ah + (size_t)(rowBase + r) * KDIM + kbase + kofs_st;
        _Float16* lA = lsA + (slot << 9);     // wave-uniform base (512 halves/slot)
        async_ld16(gA, lA);
        const _Float16* gB = Bh + (size_t)(colBase + r) * KDIM + kbase + kofs_st;
        _Float16* lB = lsB + (slot << 9);
        async_ld16(gB, lB);
      }
      __syncthreads();
      #pragma unroll
      for (int ks = 0; ks < 2; ++ks) {
        const int c0 = ks * 4 + kg;           // wanted global chunk
        const int sw = (c0 ^ frs) * 8;        // swizzled LDS slot (halves)
        half8 af[4], bf[4];
        #pragma unroll
        for (int i = 0; i < 4; i++) {
          const int arow = wr * 64 + i * 16 + fr;
          af[i] = *(const half8*)(lsA + arow * BK + sw);
          const int bcol = wc * 64 + i * 16 + fr;
          bf[i] = *(const half8*)(lsB + bcol * BK + sw);
        }
        #pragma unroll
        for (int i = 0; i < 4; i++)
          #pragma unroll
          for (int j = 0; j < 4; j++)
            acc[i][j] = __builtin_amdgcn_mfma_f32_16x16x32_f16(af[i], bf[j], acc[i][j], 0, 0, 0);
      }
      __syncthreads();
    }

    // Epilogue: cand = sq2[col] - 2*inner, fold into per-row running min.
    // C frag: col = lane&15, row = (lane>>4)*4 + reg.
    #pragma unroll
    for (int j = 0; j < 4; j++) {
      const int col = colBase + wc * 64 + j * 16 + fr;
      const float s2 = sq2[col];
      #pragma unroll
      for (int i = 0; i < 4; i++)
        #pragma unroll
        for (int r4 = 0; r4 < 4; r4++) {
          const float cand = fmaf(-2.f, acc[i][j][r4], s2);
          runmin[i][r4] = fminf(runmin[i][r4], cand);
        }
    }
  }

  // Min across the 16 columns held by a lane-group: butterfly over lane bits 0..3.
  #pragma unroll
  for (int i = 0; i < 4; i++)
    #pragma unroll
    for (int r4 = 0; r4 < 4; r4++) {
      float v = runmin[i][r4];
      v = fminf(v, __shfl_xor(v, 1, 64));
      v = fminf(v, __shfl_xor(v, 2, 64));
      v = fminf(v, __shfl_xor(v, 4, 64));
      v = fminf(v, __shfl_xor(v, 8, 64));
      runmin[i][r4] = v;
    }

  // Combine across the 2 column-waves via LDS, then write per-chunk row mins.
  if (fr == 0) {
    #pragma unroll
    for (int i = 0; i < 4; i++)
      #pragma unroll
      for (int r4 = 0; r4 < 4; r4++) {
        const int lrow = wr * 64 + i * 16 + (lane >> 4) * 4 + r4;
        lmin[wc][lrow] = runmin[i][r4];
      }
  }
  __syncthreads();
  if (tid < BM) {
    const float m = fminf(lmin[0][tid], lmin[1][tid]);
    ws_min[(size_t)chunk * N_ROWS + rowBase + tid] = m;
  }
}

// Kernel 3: final reduction across chunks + sqrt/relu/mean.
__global__ void final_kernel(const float* __restrict__ ws_min,
                             const float* __restrict__ sq1,
                             float* __restrict__ out) {
  float sum = 0.f;
  for (int r = threadIdx.x; r < N_ROWS; r += 1024) {
    float m = ws_min[r];
    #pragma unroll
    for (int c = 1; c < NCHUNK; c++) m = fminf(m, ws_min[(size_t)c * N_ROWS + r]);
    float d2 = sq1[r] + m;
    d2 = d2 > 0.f ? d2 : 0.f;
    float v = sqrtf(d2) - 0.1f;
    sum += v > 0.f ? v : 0.f;
  }
  #pragma unroll
  for (int off = 32; off; off >>= 1) sum += __shfl_down(sum, off, 64);
  __shared__ float ps[16];
  if ((threadIdx.x & 63) == 0) ps[threadIdx.x >> 6] = sum;
  __syncthreads();
  if (threadIdx.x == 0) {
    float t = 0.f;
    #pragma unroll
    for (int i = 0; i < 16; i++) t += ps[i];
    out[0] = t / (float)N_ROWS;
  }
}

extern "C" void kernel_launch(void* const* d_in, const int* in_sizes, int n_in,
                              void* d_out, int out_size, void* d_ws, size_t ws_size,
                              hipStream_t stream) {
  const float* A = (const float*)d_in[0];
  const float* B = (const float*)d_in[1];
  char* ws = (char*)d_ws;
  const size_t halfBytes = (size_t)N_ROWS * KDIM * 2;  // 16 MiB each
  _Float16* Ah = (_Float16*)ws;
  _Float16* Bh = (_Float16*)(ws + halfBytes);
  float* sq1 = (float*)(ws + 2 * halfBytes);
  float* sq2 = sq1 + N_ROWS;
  float* ws_min = sq2 + M_ROWS;

  conv_kernel<<<dim3(N_ROWS + M_ROWS), dim3(128), 0, stream>>>(A, B, Ah, Bh, sq1, sq2);
  gemm_min_kernel<<<dim3(N_ROWS / BM, NCHUNK), dim3(256), 0, stream>>>(Ah, Bh, sq2, ws_min);
  final_kernel<<<dim3(1), dim3(1024), 0, stream>>>(ws_min, sq1, (float*)d_out);
}

// Round 3
// 356.957 us; speedup vs baseline: 1.3659x; 1.3608x over previous
//
#include <hip/hip_runtime.h>
#include <stdint.h>

#define N_ROWS 16384
#define M_ROWS 16384
#define KDIM   512
#define BM 128
#define BN 128
#define BK 64
#define NCHUNK 8
#define CHUNK_ROWS (M_ROWS / NCHUNK)      // 2048
#define BT_PER_CHUNK (CHUNK_ROWS / BN)    // 16

typedef _Float16 half8 __attribute__((ext_vector_type(8)));
typedef float floatx4 __attribute__((ext_vector_type(4)));

__device__ __forceinline__ void async_ld16(const _Float16* g, _Float16* l) {
  __builtin_amdgcn_global_load_lds(
      (const __attribute__((address_space(1))) void*)g,
      (__attribute__((address_space(3))) void*)l, 16, 0, 0);
}

// Kernel 1: fp32 -> f16 + per-row squared norms. One wave per row.
__global__ void conv_kernel(const float* __restrict__ A, const float* __restrict__ B,
                            _Float16* __restrict__ Ah, _Float16* __restrict__ Bh,
                            float* __restrict__ sq1, float* __restrict__ sq2) {
  const int lane = threadIdx.x & 63;
  const int wv = threadIdx.x >> 6;
  int row = blockIdx.x * 4 + wv;
  const float* src;
  _Float16* dst;
  float* sq;
  if (row < N_ROWS) {
    src = A + (size_t)row * KDIM;
    dst = Ah + (size_t)row * KDIM;
    sq = sq1 + row;
  } else {
    int r = row - N_ROWS;
    src = B + (size_t)r * KDIM;
    dst = Bh + (size_t)r * KDIM;
    sq = sq2 + r;
  }
  const float4* s4 = (const float4*)src;
  uint2* d2 = (uint2*)dst;
  float s = 0.f;
  #pragma unroll
  for (int h = 0; h < 2; h++) {
    float4 v = s4[lane + h * 64];
    union { _Float16 hh[4]; uint2 u; } pk;
    pk.hh[0] = (_Float16)v.x; pk.hh[1] = (_Float16)v.y;
    pk.hh[2] = (_Float16)v.z; pk.hh[3] = (_Float16)v.w;
    d2[lane + h * 64] = pk.u;
    s += v.x * v.x + v.y * v.y + v.z * v.z + v.w * v.w;
  }
  #pragma unroll
  for (int off = 32; off; off >>= 1) s += __shfl_down(s, off, 64);
  if (lane == 0) *sq = s;
}

// Kernel 2: fused GEMM + running-min.
// A held persistently in registers (wave wv owns rows [wv*32, wv*32+32), 128 VGPRs).
// Only B streams through LDS: double-buffered 2 x 16KB, XOR-swizzled chunks
// (row r slot s holds global chunk s^(r&7)) to keep ds_read_b128 conflict-free.
// 1-D grid: chunk = bid & 7 pins each B-chunk (2MB) to one XCD's L2.
__global__ void __launch_bounds__(256, 2)
gemm_min_kernel(const _Float16* __restrict__ Ah, const _Float16* __restrict__ Bh,
                const float* __restrict__ sq2, float* __restrict__ ws_min) {
  __shared__ __align__(16) _Float16 lsB[2][BN * BK];

  const int tid = threadIdx.x;
  const int lane = tid & 63;
  const int wv = tid >> 6;       // 0..3, owns A rows [wv*32, wv*32+32)
  const int fr = lane & 15;
  const int kg = lane >> 4;      // 0..3
  const int frs = fr & 7;

  const int bid = blockIdx.x;
  const int chunk = bid & 7;     // == XCD under bid%8 round-robin
  const int rowBase = (bid >> 3) * BM;
  const int colBase0 = chunk * CHUNK_ROWS;

  // Staging geometry: per wave-call c, slot = wv*4+c covers 8 rows.
  const int r_st = lane >> 3;              // row-in-slot 0..7
  const int s_st = lane & 7;               // 16B-chunk-in-row 0..7
  const int kofs_st = ((s_st ^ r_st) * 8); // swizzled source chunk (halves)

  // ---- Load persistent A fragments (once): areg[i][kf] covers rows
  // wv*32 + i*16 + fr, k = kf*32 + kg*8 .. +8.  2 x 16 = 32 half8 = 128 VGPRs.
  half8 areg[2][16];
  {
    const _Float16* abase = Ah + (size_t)(rowBase + wv * 32 + fr) * KDIM + kg * 8;
    #pragma unroll
    for (int i = 0; i < 2; i++)
      #pragma unroll
      for (int kf = 0; kf < 16; kf++)
        areg[i][kf] = *(const half8*)(abase + (size_t)i * 16 * KDIM + kf * 32);
  }

  float runmin[2][4];
  #pragma unroll
  for (int i = 0; i < 2; i++)
    #pragma unroll
    for (int r4 = 0; r4 < 4; r4++) runmin[i][r4] = 3.0e38f;

  // Prologue: stage first B slice into buf 0.
  {
    #pragma unroll
    for (int c = 0; c < 4; ++c) {
      const int slot = wv * 4 + c;
      const int r = slot * 8 + r_st;
      async_ld16(Bh + (size_t)(colBase0 + r) * KDIM + kofs_st, lsB[0] + (slot << 9));
    }
  }
  __syncthreads();

  for (int bt = 0; bt < BT_PER_CHUNK; ++bt) {
    const int colBase = colBase0 + bt * BN;
    floatx4 acc[2][8];
    #pragma unroll
    for (int i = 0; i < 2; i++)
      #pragma unroll
      for (int j = 0; j < 8; j++) acc[i][j] = (floatx4){0.f, 0.f, 0.f, 0.f};

    #pragma unroll
    for (int kb = 0; kb < 8; ++kb) {
      const _Float16* cur = lsB[kb & 1];
      // Prefetch next phase into the other buffer (flies during the MFMAs).
      if (kb < 7) {
        const int kbase = (kb + 1) * BK;
        #pragma unroll
        for (int c = 0; c < 4; ++c) {
          const int slot = wv * 4 + c;
          const int r = slot * 8 + r_st;
          async_ld16(Bh + (size_t)(colBase + r) * KDIM + kbase + kofs_st,
                     lsB[(kb + 1) & 1] + (slot << 9));
        }
      } else if (bt + 1 < BT_PER_CHUNK) {
        #pragma unroll
        for (int c = 0; c < 4; ++c) {
          const int slot = wv * 4 + c;
          const int r = slot * 8 + r_st;
          async_ld16(Bh + (size_t)(colBase + BN + r) * KDIM + kofs_st,
                     lsB[0] + (slot << 9));
        }
      }
      // Compute phase kb from cur + A registers.
      #pragma unroll
      for (int j = 0; j < 8; j++) {
        const int rowoff = (j * 16 + fr) * BK;
        half8 bf0 = *(const half8*)(cur + rowoff + ((kg ^ frs) << 3));
        half8 bf1 = *(const half8*)(cur + rowoff + (((4 + kg) ^ frs) << 3));
        acc[0][j] = __builtin_amdgcn_mfma_f32_16x16x32_f16(areg[0][2 * kb], bf0, acc[0][j], 0, 0, 0);
        acc[1][j] = __builtin_amdgcn_mfma_f32_16x16x32_f16(areg[1][2 * kb], bf0, acc[1][j], 0, 0, 0);
        acc[0][j] = __builtin_amdgcn_mfma_f32_16x16x32_f16(areg[0][2 * kb + 1], bf1, acc[0][j], 0, 0, 0);
        acc[1][j] = __builtin_amdgcn_mfma_f32_16x16x32_f16(areg[1][2 * kb + 1], bf1, acc[1][j], 0, 0, 0);
      }
      __syncthreads();  // drains prefetch + publishes next buffer
    }

    // Epilogue: cand = sq2[col] - 2*inner -> per-row running min.
    // C frag: col = lane&15, row = wv*32 + i*16 + (lane>>4)*4 + reg.
    #pragma unroll
    for (int j = 0; j < 8; j++) {
      const float s2 = sq2[colBase + j * 16 + fr];
      #pragma unroll
      for (int i = 0; i < 2; i++)
        #pragma unroll
        for (int r4 = 0; r4 < 4; r4++) {
          const float cand = fmaf(-2.f, acc[i][j][r4], s2);
          runmin[i][r4] = fminf(runmin[i][r4], cand);
        }
    }
  }

  // Min over the 16 columns in each lane row-group: butterfly on lane bits 0..3.
  #pragma unroll
  for (int i = 0; i < 2; i++)
    #pragma unroll
    for (int r4 = 0; r4 < 4; r4++) {
      float v = runmin[i][r4];
      v = fminf(v, __shfl_xor(v, 1, 64));
      v = fminf(v, __shfl_xor(v, 2, 64));
      v = fminf(v, __shfl_xor(v, 4, 64));
      v = fminf(v, __shfl_xor(v, 8, 64));
      runmin[i][r4] = v;
    }

  // Each wave owns distinct rows -> write directly, no cross-wave combine.
  if (fr == 0) {
    #pragma unroll
    for (int i = 0; i < 2; i++)
      #pragma unroll
      for (int r4 = 0; r4 < 4; r4++) {
        const int lrow = wv * 32 + i * 16 + kg * 4 + r4;
        ws_min[(size_t)chunk * N_ROWS + rowBase + lrow] = runmin[i][r4];
      }
  }
}

// Kernel 3: final reduction across chunks + sqrt/relu/mean.
__global__ void final_kernel(const float* __restrict__ ws_min,
                             const float* __restrict__ sq1,
                             float* __restrict__ out) {
  float sum = 0.f;
  for (int r = threadIdx.x; r < N_ROWS; r += 1024) {
    float m = ws_min[r];
    #pragma unroll
    for (int c = 1; c < NCHUNK; c++) m = fminf(m, ws_min[(size_t)c * N_ROWS + r]);
    float d2 = sq1[r] + m;
    d2 = d2 > 0.f ? d2 : 0.f;
    float v = sqrtf(d2) - 0.1f;
    sum += v > 0.f ? v : 0.f;
  }
  #pragma unroll
  for (int off = 32; off; off >>= 1) sum += __shfl_down(sum, off, 64);
  __shared__ float ps[16];
  if ((threadIdx.x & 63) == 0) ps[threadIdx.x >> 6] = sum;
  __syncthreads();
  if (threadIdx.x == 0) {
    float t = 0.f;
    #pragma unroll
    for (int i = 0; i < 16; i++) t += ps[i];
    out[0] = t / (float)N_ROWS;
  }
}

extern "C" void kernel_launch(void* const* d_in, const int* in_sizes, int n_in,
                              void* d_out, int out_size, void* d_ws, size_t ws_size,
                              hipStream_t stream) {
  const float* A = (const float*)d_in[0];
  const float* B = (const float*)d_in[1];
  char* ws = (char*)d_ws;
  const size_t halfBytes = (size_t)N_ROWS * KDIM * 2;  // 16 MiB each
  _Float16* Ah = (_Float16*)ws;
  _Float16* Bh = (_Float16*)(ws + halfBytes);
  float* sq1 = (float*)(ws + 2 * halfBytes);
  float* sq2 = sq1 + N_ROWS;
  float* ws_min = sq2 + M_ROWS;

  conv_kernel<<<dim3((N_ROWS + M_ROWS) / 4), dim3(256), 0, stream>>>(A, B, Ah, Bh, sq1, sq2);
  gemm_min_kernel<<<dim3((N_ROWS / BM) * NCHUNK), dim3(256), 0, stream>>>(Ah, Bh, sq2, ws_min);
  final_kernel<<<dim3(1), dim3(1024), 0, stream>>>(ws_min, sq1, (float*)d_out);
}